// Round 6
// baseline (393.898 us; speedup 1.0000x reference)
//
#include <hip/hip_runtime.h>
#include <hip/hip_bf16.h>

#define D_MODEL 1024
#define N_HEAD  16
#define HD      64
#define T_SEQ   2048
#define B_SZ    4
#define M_ROWS  (B_SZ * T_SEQ)   // 8192

typedef __bf16 bf16;
typedef __bf16 bf16x4 __attribute__((ext_vector_type(4)));
typedef __bf16 bf16x8 __attribute__((ext_vector_type(8)));
typedef float  floatx4 __attribute__((ext_vector_type(4)));

__device__ __forceinline__ floatx4 fzero4() {
    floatx4 z = {0.f, 0.f, 0.f, 0.f};
    return z;
}

__device__ __forceinline__ bf16x8 cvt8(const float4 a, const float4 b) {
    bf16x8 o;
    o[0] = (bf16)a.x; o[1] = (bf16)a.y; o[2] = (bf16)a.z; o[3] = (bf16)a.w;
    o[4] = (bf16)b.x; o[5] = (bf16)b.y; o[6] = (bf16)b.z; o[7] = (bf16)b.w;
    return o;
}

// async global->LDS, 16B/lane. LDS dest = wave-uniform base + lane*16.
__device__ __forceinline__ void async_ld16(const void* g, void* l) {
    __builtin_amdgcn_global_load_lds(
        (const __attribute__((address_space(1))) void*)g,
        (__attribute__((address_space(3))) void*)l,
        16, 0, 0);
}

// tiny fp32->bf16 convert for the 4 weight matrices (4 MB each fp32)
struct CvtWArgs {
    const float* s[4];
    bf16* d[4];
};
__global__ __launch_bounds__(256) void cvtw_kernel(CvtWArgs a)
{
    const float* src = a.s[blockIdx.y];
    bf16* dst = a.d[blockIdx.y];
    const int n8 = D_MODEL * D_MODEL / 8;   // 131072
    int i = blockIdx.x * blockDim.x + threadIdx.x;
    int stride = gridDim.x * blockDim.x;
    for (; i < n8; i += stride) {
        float4 x = ((const float4*)src)[2 * i];
        float4 y = ((const float4*)src)[2 * i + 1];
        ((bf16x8*)dst)[i] = cvt8(x, y);
    }
}

struct GemmArgs {
    const void* A[3];     // fp32 (AF32=1) or bf16 (AF32=0), [M,1024]
    const bf16* W[3];     // bf16 [N=1024, K=1024] (nn.Linear weight, row = out-feature)
    const float* bias[3];
    void*       Out[3];
    float       scl[3];
    int         omode[3]; // 0: bf16 [B,H,T,64]; 1: bf16 [B,H,64,T]; 2: fp32 [M,N]
};

// C[8192,1024] = (A @ W^T + bias) * scl.
// Grid (64, 8, z): A-sharing blocks land on the same XCD -> A fetched ~once
// (verified round 3/5: FETCH 399 -> 100 MB, ~ideal).
// Round-6 change: counted-vmcnt pipeline (T4). __syncthreads drains vmcnt(0),
// exposing the ~900cy cold-HBM latency of the streaming A every iteration
// (round 5: clean traffic but 2.6x uniform stall, MfmaUtil 14%). Now:
//  - raw s_barrier + manual counted s_waitcnt (never 0 until the tail)
//  - DEPTH-2 A prefetch in two statically-named reg sets (parity-selected),
//    so A(kt) was issued ~2 full phases before its ds_write
//  - issue order pinned [W(kt+1) gload_lds, then A(kt+2)] via sched_barrier(0);
//    invariant: wait vmcnt(AVM) at top of kt leaves exactly A(kt+1) in flight,
//    W(kt) resident, A(kt) complete.
template <int AF32>
__global__ __launch_bounds__(256, 3) void gemm_k(GemmArgs g)
{
    __shared__ bf16 ldsA[128 * 64];       // 16 KB single (barrier1 protects overwrite)
    __shared__ bf16 ldsW[2][128 * 64];    // 32 KB double-buffered

    const int z = blockIdx.z;
    const bf16* W     = g.W[z];
    const float* bias = g.bias[z];
    void* Out         = g.Out[z];
    const float scl   = g.scl[z];
    const int omode   = g.omode[z];

    const int tid  = threadIdx.x;
    const int wave = tid >> 6, lane = tid & 63;
    const int quad = lane >> 4, l15 = lane & 15;
    const int wr = wave >> 1, wc = wave & 1;
    const int m0 = blockIdx.x * 128, n0 = blockIdx.y * 128;

    floatx4 acc[4][4];
#pragma unroll
    for (int i = 0; i < 4; ++i)
#pragma unroll
        for (int j = 0; j < 4; ++j) acc[i][j] = fzero4();

    const int ro = lane >> 3;   // row-within-8
    const int c8 = lane & 7;    // chunk index

    // A: LDS write dest, XOR-swizzled slot (slot c8^ro holds chunk c8); global linear
    bf16* dA = &ldsA[(wave * 32 + ro) * 64 + (c8 ^ ro) * 8];
    const float* gAf = nullptr;
    const bf16*  gAb = nullptr;
    if constexpr (AF32)
        gAf = (const float*)g.A[z] + (size_t)(m0 + wave * 32 + ro) * 1024 + c8 * 8;
    else
        gAb = (const bf16*)g.A[z] + (size_t)(m0 + wave * 32 + ro) * 1024 + c8 * 8;

    // W: gload_lds, source pre-swizzled so linear dest realizes slot c = chunk c^ro
    const bf16* gW = W + (size_t)(n0 + wave * 32 + ro) * 1024 + (c8 ^ ro) * 8;

    // two statically-named A staging sets (rule #20: no runtime-indexed reg arrays)
    float4 raf0[4][2], raf1[4][2];
    bf16x8 rab0[4],    rab1[4];

#define LOAD_A_SET(RAF, RAB, OFF)                                              \
    do {                                                                       \
        if constexpr (AF32) {                                                  \
            _Pragma("unroll")                                                  \
            for (int j = 0; j < 4; ++j) {                                      \
                RAF[j][0] = *(const float4*)(gAf + (OFF) + (size_t)j * 8192);  \
                RAF[j][1] = *(const float4*)(gAf + (OFF) + (size_t)j * 8192 + 4);\
            }                                                                  \
        } else {                                                               \
            _Pragma("unroll")                                                  \
            for (int j = 0; j < 4; ++j)                                        \
                RAB[j] = *(const bf16x8*)(gAb + (OFF) + (size_t)j * 8192);     \
        }                                                                      \
    } while (0)

#define DSW_A_SET(RAF, RAB)                                                    \
    do {                                                                       \
        _Pragma("unroll")                                                      \
        for (int j = 0; j < 4; ++j) {                                          \
            if constexpr (AF32)                                                \
                *(bf16x8*)(dA + j * 8 * 64) = cvt8(RAF[j][0], RAF[j][1]);      \
            else                                                               \
                *(bf16x8*)(dA + j * 8 * 64) = RAB[j];                          \
        }                                                                      \
    } while (0)

    // prologue: issue order [A(0), W(0), A(1)] so wait(AVM) at kt=0 leaves A(1)
    LOAD_A_SET(raf0, rab0, 0);
    __builtin_amdgcn_sched_barrier(0);
#pragma unroll
    for (int j = 0; j < 4; ++j)
        async_ld16((const void*)(gW + (size_t)j * 8192), &ldsW[0][(wave * 32 + j * 8) * 64]);
    __builtin_amdgcn_sched_barrier(0);
    LOAD_A_SET(raf1, rab1, 64);
    __builtin_amdgcn_sched_barrier(0);

    for (int kt = 0; kt < 16; ++kt) {
        const int cur = kt & 1;
        __builtin_amdgcn_s_barrier();       // waves done reading prev ldsA/ldsW
        if (kt < 15) {
            // counted: leave A(kt+1)'s loads in flight; W(kt) + A(kt) forced done
            if constexpr (AF32) asm volatile("s_waitcnt vmcnt(8)" ::: "memory");
            else                asm volatile("s_waitcnt vmcnt(4)" ::: "memory");
        } else {
            asm volatile("s_waitcnt vmcnt(0)" ::: "memory");
        }
        __builtin_amdgcn_sched_barrier(0);

        // ds_write A(kt) from set[kt&1]
        if (cur == 0) DSW_A_SET(raf0, rab0);
        else          DSW_A_SET(raf1, rab1);

        // issue W(kt+1) -> ldsW[cur^1]  (MUST precede A(kt+2) for the count invariant)
        if (kt < 15) {
            const int woff = (kt + 1) * 64;
#pragma unroll
            for (int j = 0; j < 4; ++j)
                async_ld16((const void*)(gW + woff + (size_t)j * 8192),
                           &ldsW[cur ^ 1][(wave * 32 + j * 8) * 64]);
        }
        __builtin_amdgcn_sched_barrier(0);

        // issue A(kt+2) -> set[kt&1] (regs just consumed by the ds_write above)
        if (kt < 14) {
            const int aoff = (kt + 2) * 64;
            if (cur == 0) LOAD_A_SET(raf0, rab0, aoff);
            else          LOAD_A_SET(raf1, rab1, aoff);
        }
        __builtin_amdgcn_sched_barrier(0);

        asm volatile("s_waitcnt lgkmcnt(0)" ::: "memory");   // own ds_writes done
        __builtin_amdgcn_s_barrier();                        // staged A visible
        __builtin_amdgcn_sched_barrier(0);

        const bf16* wcur = ldsW[cur];
#pragma unroll
        for (int ks = 0; ks < 2; ++ks) {
            const int pos = ((ks * 4 + quad) ^ (l15 & 7)) * 8;
            bf16x8 af[4], bw[4];
#pragma unroll
            for (int i = 0; i < 4; ++i)
                af[i] = *(const bf16x8*)(&ldsA[(wr * 64 + i * 16 + l15) * 64 + pos]);
#pragma unroll
            for (int j = 0; j < 4; ++j)
                bw[j] = *(const bf16x8*)(&wcur[(wc * 64 + j * 16 + l15) * 64 + pos]);
#pragma unroll
            for (int i = 0; i < 4; ++i)
#pragma unroll
                for (int j = 0; j < 4; ++j)
                    acc[i][j] = __builtin_amdgcn_mfma_f32_16x16x32_bf16(af[i], bw[j], acc[i][j], 0, 0, 0);
        }
    }
#undef LOAD_A_SET
#undef DSW_A_SET

#pragma unroll
    for (int i = 0; i < 4; ++i) {
#pragma unroll
        for (int j = 0; j < 4; ++j) {
#pragma unroll
            for (int r = 0; r < 4; ++r) {
                int m = m0 + wr * 64 + i * 16 + quad * 4 + r;
                int n = n0 + wc * 64 + j * 16 + l15;
                float val = (acc[i][j][r] + bias[n]) * scl;
                if (omode == 2) {
                    ((float*)Out)[(size_t)m * 1024 + n] = val;
                } else {
                    int b = m >> 11, t = m & 2047;
                    int h = n >> 6,  d = n & 63;
                    size_t addr;
                    if (omode == 0)
                        addr = ((size_t)(b * N_HEAD + h) * T_SEQ + t) * HD + d;
                    else
                        addr = ((size_t)(b * N_HEAD + h) * HD + d) * T_SEQ + t;
                    ((bf16*)Out)[addr] = (bf16)val;
                }
            }
        }
    }
}

// Flash-style causal attention, S^T formulation, paired q-tiles for perfect balance.
// Qh (pre-scaled by 1/8*log2e), Kh: [B,H,T,64] bf16.  Vt: [B,H,64,T] bf16.  AO: [B,T,D] bf16.
// T14 async-STAGE split + T5 setprio + T13 defer-max (verified round 1: 110.9->91.5 us).
__global__ __launch_bounds__(256, 2) void attn_kernel(
    const bf16* __restrict__ Qh, const bf16* __restrict__ Kh,
    const bf16* __restrict__ Vt, bf16* __restrict__ AO)
{
    __shared__ bf16 Ks[128 * 64];   // 16 KB, XOR-swizzled chunks (slot c holds chunk c^(r&7))
    __shared__ bf16 Vts[64 * 128];  // 16 KB, XOR-swizzled (slot c holds chunk c^(d&15))
    __shared__ bf16 Ps[128 * 72];   // 18 KB, half-k P buffer (2-pass), wave-private rows

    const int tid  = threadIdx.x;
    const int wave = tid >> 6, lane = tid & 63;
    const int quad = lane >> 4, l15 = lane & 15;
    const int bh = blockIdx.y;
    const size_t base = (size_t)bh * T_SEQ * HD;
    const int bb = bh >> 4, hh = bh & 15;

    // staging lane->addr precompute (global source pre-swizzled, LDS dest swizzled slot)
    const int kro = lane >> 3;
    const int kgc = (lane & 7) ^ kro;
    const bf16* kgbase = Kh + base + (size_t)(wave * 32 + kro) * HD + kgc * 8;
    const int vrow_lo = lane >> 4;
    const int vchunk  = lane & 15;

    const bf16* vgbase[4];
    bf16* kdst[4];
    bf16* vdst[4];
#pragma unroll
    for (int j = 0; j < 4; ++j) {
        int d = wave * 16 + j * 4 + vrow_lo;
        int gcv = vchunk ^ (d & 15);
        vgbase[j] = Vt + base + (size_t)d * T_SEQ + gcv * 8;
        vdst[j]   = &Vts[d * 128 + vchunk * 8];
        kdst[j]   = &Ks[(wave * 32 + j * 8 + kro) * 64 + (lane & 7) * 8];
    }

    for (int phase = 0; phase < 2; ++phase) {
        const int qt = phase ? blockIdx.x : 15 - blockIdx.x;

        // Q fragments (pre-scaled), B-operand layout: lane l15 = q, k = quad*8+j
        bf16x8 qf[2][2];
        const bf16* qbase = Qh + base + (size_t)(qt * 128 + wave * 32) * HD;
#pragma unroll
        for (int ti = 0; ti < 2; ++ti)
#pragma unroll
            for (int ks = 0; ks < 2; ++ks)
                qf[ti][ks] = *(const bf16x8*)(qbase + (ti * 16 + l15) * HD + ks * 32 + quad * 8);

        // prologue: issue reg-loads for kt=0 (latency exposed once per phase)
        bf16x8 kreg[4], vreg[4];
#pragma unroll
        for (int j = 0; j < 4; ++j)
            kreg[j] = *(const bf16x8*)(kgbase + (size_t)(j * 8) * HD);
#pragma unroll
        for (int j = 0; j < 4; ++j)
            vreg[j] = *(const bf16x8*)(vgbase[j]);

        float mrow[2] = {-1e30f, -1e30f}, lrow[2] = {0.f, 0.f};
        floatx4 oacc[2][4];
#pragma unroll
        for (int ti = 0; ti < 2; ++ti)
#pragma unroll
            for (int nj = 0; nj < 4; ++nj) oacc[ti][nj] = fzero4();

        for (int kt = 0; kt <= qt; ++kt) {
            __syncthreads();   // all waves done reading Ks/Vts; vmcnt drain -> kreg/vreg ready
#pragma unroll
            for (int j = 0; j < 4; ++j) *(bf16x8*)kdst[j] = kreg[j];
#pragma unroll
            for (int j = 0; j < 4; ++j) *(bf16x8*)vdst[j] = vreg[j];
            __syncthreads();   // staged tile visible

            // T14: issue next tile's loads NOW; they complete under the compute below
            if (kt < qt) {
#pragma unroll
                for (int j = 0; j < 4; ++j)
                    kreg[j] = *(const bf16x8*)(kgbase + (size_t)((kt + 1) * 128 + j * 8) * HD);
#pragma unroll
                for (int j = 0; j < 4; ++j)
                    vreg[j] = *(const bf16x8*)(vgbase[j] + (kt + 1) * 128);
            }

            const bool diag = (kt == qt);
            const int lim = diag ? (2 * wave + 1) : 7;   // max tj with any unmasked k

            // S^T = K Q^T : A = K-frag (l15 = k-row), B = Q-frag (l15 = q)
            floatx4 sacc[2][8];
#pragma unroll
            for (int ti = 0; ti < 2; ++ti)
#pragma unroll
                for (int tj = 0; tj < 8; ++tj) sacc[ti][tj] = fzero4();
            __builtin_amdgcn_s_setprio(1);
#pragma unroll
            for (int ks = 0; ks < 2; ++ks) {
                const int pos = ((ks * 4 + quad) ^ (l15 & 7)) * 8;
#pragma unroll
                for (int tj = 0; tj < 8; ++tj) {
                    if (tj <= lim) {
                        bf16x8 kf = *(const bf16x8*)(&Ks[(tj * 16 + l15) * 64 + pos]);
                        sacc[0][tj] = __builtin_amdgcn_mfma_f32_16x16x32_bf16(kf, qf[0][ks], sacc[0][tj], 0, 0, 0);
                        sacc[1][tj] = __builtin_amdgcn_mfma_f32_16x16x32_bf16(kf, qf[1][ks], sacc[1][tj], 0, 0, 0);
                    }
                }
            }
            __builtin_amdgcn_s_setprio(0);

            // online softmax (scores pre-scaled): lane owns q = l15 (per ti)
#pragma unroll
            for (int ti = 0; ti < 2; ++ti) {
                const int ql = wave * 32 + ti * 16 + l15;
                float mxp[4] = {-1e30f, -1e30f, -1e30f, -1e30f};
#pragma unroll
                for (int tj = 0; tj < 8; ++tj) {
                    if (tj <= lim) {
#pragma unroll
                        for (int r = 0; r < 4; ++r) {
                            float s = sacc[ti][tj][r];
                            if (diag && (tj * 16 + quad * 4 + r) > ql) s = -1e30f;
                            sacc[ti][tj][r] = s;
                            mxp[r] = fmaxf(mxp[r], s);
                        }
                    }
                }
                float mx = fmaxf(fmaxf(mxp[0], mxp[1]), fmaxf(mxp[2], mxp[3]));
                mx = fmaxf(mx, __shfl_xor(mx, 16));
                mx = fmaxf(mx, __shfl_xor(mx, 32));
                // T13 defer-max: only rescale when some row's max grew by >8 (log2)
                if (__any(mx > mrow[ti] + 8.0f)) {
                    float mnew  = fmaxf(mrow[ti], mx);
                    float alpha = exp2f(mrow[ti] - mnew);
                    mrow[ti] = mnew;
                    lrow[ti] *= alpha;
#pragma unroll
                    for (int r = 0; r < 4; ++r) {
                        float ar = __shfl(alpha, quad * 4 + r);
#pragma unroll
                        for (int nj = 0; nj < 4; ++nj)
                            oacc[ti][nj][r] *= ar;
                    }
                }
                float rs[4] = {0.f, 0.f, 0.f, 0.f};
#pragma unroll
                for (int tj = 0; tj < 8; ++tj) {
                    if (tj <= lim) {
#pragma unroll
                        for (int r = 0; r < 4; ++r) {
                            float p = exp2f(sacc[ti][tj][r] - mrow[ti]);
                            rs[r] += p;
                            sacc[ti][tj][r] = p;
                        }
                    }
                }
                float rsum = (rs[0] + rs[1]) + (rs[2] + rs[3]);
                rsum += __shfl_xor(rsum, 16);
                rsum += __shfl_xor(rsum, 32);
                lrow[ti] += rsum;
            }

            // P -> LDS and O += P V, in two k-halves (Ps wave-private rows)
#pragma unroll
            for (int h2 = 0; h2 < 2; ++h2) {
                if (4 * h2 > lim) break;
#pragma unroll
                for (int ti = 0; ti < 2; ++ti) {
                    const int ql = wave * 32 + ti * 16 + l15;
#pragma unroll
                    for (int tjo = 0; tjo < 4; ++tjo) {
                        int tj = 4 * h2 + tjo;
                        if (tj <= lim) {
                            bf16x4 pv;
#pragma unroll
                            for (int r = 0; r < 4; ++r) pv[r] = (bf16)sacc[ti][tj][r];
                            *(bf16x4*)(&Ps[ql * 72 + tjo * 16 + quad * 4]) = pv;
                        }
                    }
                }
#pragma unroll
                for (int ks2 = 0; ks2 < 2; ++ks2) {
                    const int gks = 2 * h2 + ks2;
                    if (diag && gks > wave) break;
                    bf16x8 pf[2];
                    pf[0] = *(const bf16x8*)(&Ps[(wave * 32 + l15) * 72 + ks2 * 32 + quad * 8]);
                    pf[1] = *(const bf16x8*)(&Ps[(wave * 32 + 16 + l15) * 72 + ks2 * 32 + quad * 8]);
                    __builtin_amdgcn_s_setprio(1);
#pragma unroll
                    for (int nj = 0; nj < 4; ++nj) {
                        int pos = ((gks * 4 + quad) ^ l15) * 8;
                        bf16x8 vf = *(const bf16x8*)(&Vts[(nj * 16 + l15) * 128 + pos]);
                        oacc[0][nj] = __builtin_amdgcn_mfma_f32_16x16x32_bf16(pf[0], vf, oacc[0][nj], 0, 0, 0);
                        oacc[1][nj] = __builtin_amdgcn_mfma_f32_16x16x32_bf16(pf[1], vf, oacc[1][nj], 0, 0, 0);
                    }
                    __builtin_amdgcn_s_setprio(0);
                }
            }
        }

        // epilogue: O /= l ; O rows = quad*4+r, cols d = nj*16+l15
#pragma unroll
        for (int ti = 0; ti < 2; ++ti) {
#pragma unroll
            for (int r = 0; r < 4; ++r) {
                float lv = __shfl(lrow[ti], quad * 4 + r);
                float rl = 1.f / lv;
                int qrow = qt * 128 + wave * 32 + ti * 16 + quad * 4 + r;
#pragma unroll
                for (int nj = 0; nj < 4; ++nj) {
                    int d = nj * 16 + l15;
                    AO[((size_t)(bb * T_SEQ + qrow)) * D_MODEL + hh * HD + d] =
                        (bf16)(oacc[ti][nj][r] * rl);
                }
            }
        }
    }
}

extern "C" void kernel_launch(void* const* d_in, const int* in_sizes, int n_in,
                              void* d_out, int out_size, void* d_ws, size_t ws_size,
                              hipStream_t stream)
{
    const float* q  = (const float*)d_in[0];
    const float* k  = (const float*)d_in[1];
    const float* v  = (const float*)d_in[2];
    const float* wq = (const float*)d_in[3];
    const float* bq = (const float*)d_in[4];
    const float* wk = (const float*)d_in[5];
    const float* bk = (const float*)d_in[6];
    const float* wv = (const float*)d_in[7];
    const float* bv = (const float*)d_in[8];
    const float* wo = (const float*)d_in[9];
    const float* bo = (const float*)d_in[10];

    char* ws  = (char*)d_ws;
    char* dob = (char*)d_out;
    const size_t MB = 1024 * 1024;

    // ws: Wqb[0,2) Wkb[2,4) Wvb[4,6) AO[6,22) Qh[22,38) Kh[38,54) Wob[54,56)
    // d_out (32 MB): Vt[0,16) bf16 during QKV+attn, then final fp32 out.
    bf16* Wqb = (bf16*)(ws);
    bf16* Wkb = (bf16*)(ws + 2 * MB);
    bf16* Wvb = (bf16*)(ws + 4 * MB);
    bf16* AO  = (bf16*)(ws + 6 * MB);
    bf16* Qh  = (bf16*)(ws + 22 * MB);
    bf16* Kh  = (bf16*)(ws + 38 * MB);
    bf16* Wob = (bf16*)(ws + 54 * MB);
    bf16* Vt  = (bf16*)(dob);

    const float QSCALE = 0.18033688011112042f;  // (1/sqrt(64)) * log2(e)

    CvtWArgs cw;
    cw.s[0] = wq; cw.d[0] = Wqb;
    cw.s[1] = wk; cw.d[1] = Wkb;
    cw.s[2] = wv; cw.d[2] = Wvb;
    cw.s[3] = wo; cw.d[3] = Wob;

    GemmArgs gq;
    gq.A[0] = q; gq.W[0] = Wqb; gq.bias[0] = bq; gq.Out[0] = (void*)Qh; gq.scl[0] = QSCALE; gq.omode[0] = 0;
    gq.A[1] = k; gq.W[1] = Wkb; gq.bias[1] = bk; gq.Out[1] = (void*)Kh; gq.scl[1] = 1.0f;   gq.omode[1] = 0;
    gq.A[2] = v; gq.W[2] = Wvb; gq.bias[2] = bv; gq.Out[2] = (void*)Vt; gq.scl[2] = 1.0f;   gq.omode[2] = 1;

    GemmArgs go;
    go.A[0] = AO; go.W[0] = Wob; go.bias[0] = bo; go.Out[0] = d_out; go.scl[0] = 1.0f; go.omode[0] = 2;
    go.A[1] = AO; go.W[1] = Wob; go.bias[1] = bo; go.Out[1] = d_out; go.scl[1] = 1.0f; go.omode[1] = 2;
    go.A[2] = AO; go.W[2] = Wob; go.bias[2] = bo; go.Out[2] = d_out; go.scl[2] = 1.0f; go.omode[2] = 2;

    hipLaunchKernelGGL(cvtw_kernel, dim3(64, 4), dim3(256), 0, stream, cw);
    hipLaunchKernelGGL((gemm_k<1>), dim3(64, 8, 3), dim3(256), 0, stream, gq);
    hipLaunchKernelGGL(attn_kernel, dim3(8, 64), dim3(256), 0, stream, Qh, Kh, Vt, AO);
    hipLaunchKernelGGL((gemm_k<0>), dim3(64, 8, 1), dim3(256), 0, stream, go);
}

// Round 8
// 351.748 us; speedup vs baseline: 1.1198x; 1.1198x over previous
//
#include <hip/hip_runtime.h>
#include <hip/hip_bf16.h>

#define D_MODEL 1024
#define N_HEAD  16
#define HD      64
#define T_SEQ   2048
#define B_SZ    4
#define M_ROWS  (B_SZ * T_SEQ)   // 8192

typedef __bf16 bf16;
typedef __bf16 bf16x4 __attribute__((ext_vector_type(4)));
typedef __bf16 bf16x8 __attribute__((ext_vector_type(8)));
typedef float  floatx4 __attribute__((ext_vector_type(4)));

__device__ __forceinline__ floatx4 fzero4() {
    floatx4 z = {0.f, 0.f, 0.f, 0.f};
    return z;
}

__device__ __forceinline__ bf16x8 cvt8(const float4 a, const float4 b) {
    bf16x8 o;
    o[0] = (bf16)a.x; o[1] = (bf16)a.y; o[2] = (bf16)a.z; o[3] = (bf16)a.w;
    o[4] = (bf16)b.x; o[5] = (bf16)b.y; o[6] = (bf16)b.z; o[7] = (bf16)b.w;
    return o;
}

// async global->LDS, 16B/lane. LDS dest = wave-uniform base + lane*16.
__device__ __forceinline__ void async_ld16(const void* g, void* l) {
    __builtin_amdgcn_global_load_lds(
        (const __attribute__((address_space(1))) void*)g,
        (__attribute__((address_space(3))) void*)l,
        16, 0, 0);
}

// fused fp32 -> bf16 convert: 7 segments (q,k,v + 4 weights)
struct CvtArgs {
    const float* s[7];
    bf16* d[7];
    int n[7];
};
__global__ __launch_bounds__(256) void cvt7_kernel(CvtArgs a)
{
    const float* src = a.s[blockIdx.y];
    bf16* dst = a.d[blockIdx.y];
    int n8 = a.n[blockIdx.y];
    int i = blockIdx.x * blockDim.x + threadIdx.x;
    int stride = gridDim.x * blockDim.x;
    for (; i < n8; i += stride) {
        float4 x = ((const float4*)src)[2 * i];
        float4 y = ((const float4*)src)[2 * i + 1];
        ((bf16x8*)dst)[i] = cvt8(x, y);
    }
}

struct GemmArgs {
    const bf16* A[2];     // bf16 [M,1024]
    const bf16* W[2];     // bf16 [N=1024,K=1024] (nn.Linear weight, row = out-feature)
    const float* bias[2];
    void*       Out[2];
    float       scl[2];
    int         omode[2]; // 0: bf16 [B,H,T,64]; 1: bf16 [B,H,64,T]; 2: fp32 [M,N]
};

// C[8192,1024] = (A @ W^T + bias) * scl, all-bf16 inputs.
// Round-7 structure (revert of round-6's counted-vmcnt, which regressed):
//  - 256x128 tile, 512 threads (8 waves, 4x2): 64 MFMA/wave/K-step (was 32) --
//    halves the per-FLOP share of barrier/stage/addr overhead that pinned
//    MfmaUtil at 14% with the 128^2 tile (rounds 5/6).
//  - ALL staging via global_load_lds with pre-swizzled source (m97 pattern),
//    single-buffered, plain 2x __syncthreads per K-step. Zero staging VGPRs.
//  - Grid (32,8,z): A-sharing blocks (same x, 8 y's) have ids differing by
//    32 = 0 mod 8 XCDs -> same XCD L2 -> A fetched from HBM ~once (verified r3/5).
//  - launch_bounds(512,4): 2 blocks/CU (96 KB LDS), VGPR cap 128 (need ~115).
__global__ __launch_bounds__(512, 4) void gemm_k(GemmArgs g)
{
    __shared__ bf16 ldsA[256 * 64];   // 32 KB
    __shared__ bf16 ldsW[128 * 64];   // 16 KB

    const int z = blockIdx.z;
    const bf16* A     = g.A[z];
    const bf16* W     = g.W[z];
    const float* bias = g.bias[z];
    void* Out         = g.Out[z];
    const float scl   = g.scl[z];
    const int omode   = g.omode[z];

    const int tid  = threadIdx.x;
    const int wave = tid >> 6, lane = tid & 63;   // wave 0..7
    const int quad = lane >> 4, l15 = lane & 15;
    const int wr = wave >> 1, wc = wave & 1;      // 4 x 2 wave grid
    const int m0 = blockIdx.x * 256, n0 = blockIdx.y * 128;

    floatx4 acc[4][4];
#pragma unroll
    for (int i = 0; i < 4; ++i)
#pragma unroll
        for (int j = 0; j < 4; ++j) acc[i][j] = fzero4();

    const int ro = lane >> 3;   // row-within-8
    const int c8 = lane & 7;    // chunk index
    // pre-swizzled global sources: linear LDS dest slot c8 receives chunk c8^ro,
    // realizing LDS slot layout "slot c holds chunk c^(row&7)".
    const bf16* gA = A + (size_t)(m0 + wave * 32 + ro) * 1024 + (c8 ^ ro) * 8;
    const bf16* gW = W + (size_t)(n0 + wave * 16 + ro) * 1024 + (c8 ^ ro) * 8;

    for (int kt = 0; kt < 16; ++kt) {
        __syncthreads();   // all waves done reading prev tile
        // A: 8 waves x 4 groups x 8 rows = 256 rows
#pragma unroll
        for (int j = 0; j < 4; ++j)
            async_ld16((const void*)(gA + kt * 64 + (size_t)j * 8 * 1024),
                       &ldsA[(wave * 32 + j * 8) * 64]);
        // W: 8 waves x 2 groups x 8 rows = 128 rows
#pragma unroll
        for (int j = 0; j < 2; ++j)
            async_ld16((const void*)(gW + kt * 64 + (size_t)j * 8 * 1024),
                       &ldsW[(wave * 16 + j * 8) * 64]);
        __syncthreads();   // vmcnt(0) drain + barrier: tile visible

#pragma unroll
        for (int ks = 0; ks < 2; ++ks) {
            const int pos = ((ks * 4 + quad) ^ (l15 & 7)) * 8;
            bf16x8 af[4], bw[4];
#pragma unroll
            for (int i = 0; i < 4; ++i)
                af[i] = *(const bf16x8*)(&ldsA[(wr * 64 + i * 16 + l15) * 64 + pos]);
#pragma unroll
            for (int j = 0; j < 4; ++j)
                bw[j] = *(const bf16x8*)(&ldsW[(wc * 64 + j * 16 + l15) * 64 + pos]);
#pragma unroll
            for (int i = 0; i < 4; ++i)
#pragma unroll
                for (int j = 0; j < 4; ++j)
                    acc[i][j] = __builtin_amdgcn_mfma_f32_16x16x32_bf16(af[i], bw[j], acc[i][j], 0, 0, 0);
        }
    }

    // epilogue
#pragma unroll
    for (int i = 0; i < 4; ++i) {
#pragma unroll
        for (int j = 0; j < 4; ++j) {
            if (omode == 1) {
                // V^T out [B,H,64,T]: r -> t is contiguous; pack bf16x4 (8B stores)
                int m = m0 + wr * 64 + i * 16 + quad * 4;   // r=0
                int n = n0 + wc * 64 + j * 16 + l15;
                int b = m >> 11, t0 = m & 2047;
                int h = n >> 6,  d = n & 63;
                bf16x4 pv;
#pragma unroll
                for (int r = 0; r < 4; ++r)
                    pv[r] = (bf16)((acc[i][j][r] + bias[n]) * scl);
                size_t addr = ((size_t)(b * N_HEAD + h) * HD + d) * T_SEQ + t0;
                *(bf16x4*)(&((bf16*)Out)[addr]) = pv;
            } else {
#pragma unroll
                for (int r = 0; r < 4; ++r) {
                    int m = m0 + wr * 64 + i * 16 + quad * 4 + r;
                    int n = n0 + wc * 64 + j * 16 + l15;
                    float val = (acc[i][j][r] + bias[n]) * scl;
                    if (omode == 2) {
                        ((float*)Out)[(size_t)m * 1024 + n] = val;
                    } else {
                        int b = m >> 11, t = m & 2047;
                        int h = n >> 6,  d = n & 63;
                        size_t addr = ((size_t)(b * N_HEAD + h) * T_SEQ + t) * HD + d;
                        ((bf16*)Out)[addr] = (bf16)val;
                    }
                }
            }
        }
    }
}

// Flash-style causal attention, S^T formulation, paired q-tiles for perfect balance.
// Qh (pre-scaled by 1/8*log2e), Kh: [B,H,T,64] bf16.  Vt: [B,H,64,T] bf16.  AO: [B,T,D] bf16.
// T14 async-STAGE split + T5 setprio + T13 defer-max (verified round 1: 110.9->91.5 us).
__global__ __launch_bounds__(256, 2) void attn_kernel(
    const bf16* __restrict__ Qh, const bf16* __restrict__ Kh,
    const bf16* __restrict__ Vt, bf16* __restrict__ AO)
{
    __shared__ bf16 Ks[128 * 64];   // 16 KB, XOR-swizzled chunks (slot c holds chunk c^(r&7))
    __shared__ bf16 Vts[64 * 128];  // 16 KB, XOR-swizzled (slot c holds chunk c^(d&15))
    __shared__ bf16 Ps[128 * 72];   // 18 KB, half-k P buffer (2-pass), wave-private rows

    const int tid  = threadIdx.x;
    const int wave = tid >> 6, lane = tid & 63;
    const int quad = lane >> 4, l15 = lane & 15;
    const int bh = blockIdx.y;
    const size_t base = (size_t)bh * T_SEQ * HD;
    const int bb = bh >> 4, hh = bh & 15;

    // staging lane->addr precompute (global source pre-swizzled, LDS dest swizzled slot)
    const int kro = lane >> 3;
    const int kgc = (lane & 7) ^ kro;
    const bf16* kgbase = Kh + base + (size_t)(wave * 32 + kro) * HD + kgc * 8;
    const int vrow_lo = lane >> 4;
    const int vchunk  = lane & 15;

    const bf16* vgbase[4];
    bf16* kdst[4];
    bf16* vdst[4];
#pragma unroll
    for (int j = 0; j < 4; ++j) {
        int d = wave * 16 + j * 4 + vrow_lo;
        int gcv = vchunk ^ (d & 15);
        vgbase[j] = Vt + base + (size_t)d * T_SEQ + gcv * 8;
        vdst[j]   = &Vts[d * 128 + vchunk * 8];
        kdst[j]   = &Ks[(wave * 32 + j * 8 + kro) * 64 + (lane & 7) * 8];
    }

    for (int phase = 0; phase < 2; ++phase) {
        const int qt = phase ? blockIdx.x : 15 - blockIdx.x;

        // Q fragments (pre-scaled), B-operand layout: lane l15 = q, k = quad*8+j
        bf16x8 qf[2][2];
        const bf16* qbase = Qh + base + (size_t)(qt * 128 + wave * 32) * HD;
#pragma unroll
        for (int ti = 0; ti < 2; ++ti)
#pragma unroll
            for (int ks = 0; ks < 2; ++ks)
                qf[ti][ks] = *(const bf16x8*)(qbase + (ti * 16 + l15) * HD + ks * 32 + quad * 8);

        // prologue: issue reg-loads for kt=0 (latency exposed once per phase)
        bf16x8 kreg[4], vreg[4];
#pragma unroll
        for (int j = 0; j < 4; ++j)
            kreg[j] = *(const bf16x8*)(kgbase + (size_t)(j * 8) * HD);
#pragma unroll
        for (int j = 0; j < 4; ++j)
            vreg[j] = *(const bf16x8*)(vgbase[j]);

        float mrow[2] = {-1e30f, -1e30f}, lrow[2] = {0.f, 0.f};
        floatx4 oacc[2][4];
#pragma unroll
        for (int ti = 0; ti < 2; ++ti)
#pragma unroll
            for (int nj = 0; nj < 4; ++nj) oacc[ti][nj] = fzero4();

        for (int kt = 0; kt <= qt; ++kt) {
            __syncthreads();   // all waves done reading Ks/Vts; vmcnt drain -> kreg/vreg ready
#pragma unroll
            for (int j = 0; j < 4; ++j) *(bf16x8*)kdst[j] = kreg[j];
#pragma unroll
            for (int j = 0; j < 4; ++j) *(bf16x8*)vdst[j] = vreg[j];
            __syncthreads();   // staged tile visible

            // T14: issue next tile's loads NOW; they complete under the compute below
            if (kt < qt) {
#pragma unroll
                for (int j = 0; j < 4; ++j)
                    kreg[j] = *(const bf16x8*)(kgbase + (size_t)((kt + 1) * 128 + j * 8) * HD);
#pragma unroll
                for (int j = 0; j < 4; ++j)
                    vreg[j] = *(const bf16x8*)(vgbase[j] + (kt + 1) * 128);
            }

            const bool diag = (kt == qt);
            const int lim = diag ? (2 * wave + 1) : 7;   // max tj with any unmasked k

            // S^T = K Q^T : A = K-frag (l15 = k-row), B = Q-frag (l15 = q)
            floatx4 sacc[2][8];
#pragma unroll
            for (int ti = 0; ti < 2; ++ti)
#pragma unroll
                for (int tj = 0; tj < 8; ++tj) sacc[ti][tj] = fzero4();
            __builtin_amdgcn_s_setprio(1);
#pragma unroll
            for (int ks = 0; ks < 2; ++ks) {
                const int pos = ((ks * 4 + quad) ^ (l15 & 7)) * 8;
#pragma unroll
                for (int tj = 0; tj < 8; ++tj) {
                    if (tj <= lim) {
                        bf16x8 kf = *(const bf16x8*)(&Ks[(tj * 16 + l15) * 64 + pos]);
                        sacc[0][tj] = __builtin_amdgcn_mfma_f32_16x16x32_bf16(kf, qf[0][ks], sacc[0][tj], 0, 0, 0);
                        sacc[1][tj] = __builtin_amdgcn_mfma_f32_16x16x32_bf16(kf, qf[1][ks], sacc[1][tj], 0, 0, 0);
                    }
                }
            }
            __builtin_amdgcn_s_setprio(0);

            // online softmax (scores pre-scaled): lane owns q = l15 (per ti)
#pragma unroll
            for (int ti = 0; ti < 2; ++ti) {
                const int ql = wave * 32 + ti * 16 + l15;
                float mxp[4] = {-1e30f, -1e30f, -1e30f, -1e30f};
#pragma unroll
                for (int tj = 0; tj < 8; ++tj) {
                    if (tj <= lim) {
#pragma unroll
                        for (int r = 0; r < 4; ++r) {
                            float s = sacc[ti][tj][r];
                            if (diag && (tj * 16 + quad * 4 + r) > ql) s = -1e30f;
                            sacc[ti][tj][r] = s;
                            mxp[r] = fmaxf(mxp[r], s);
                        }
                    }
                }
                float mx = fmaxf(fmaxf(mxp[0], mxp[1]), fmaxf(mxp[2], mxp[3]));
                mx = fmaxf(mx, __shfl_xor(mx, 16));
                mx = fmaxf(mx, __shfl_xor(mx, 32));
                // T13 defer-max: only rescale when some row's max grew by >8 (log2)
                if (__any(mx > mrow[ti] + 8.0f)) {
                    float mnew  = fmaxf(mrow[ti], mx);
                    float alpha = exp2f(mrow[ti] - mnew);
                    mrow[ti] = mnew;
                    lrow[ti] *= alpha;
#pragma unroll
                    for (int r = 0; r < 4; ++r) {
                        float ar = __shfl(alpha, quad * 4 + r);
#pragma unroll
                        for (int nj = 0; nj < 4; ++nj)
                            oacc[ti][nj][r] *= ar;
                    }
                }
                float rs[4] = {0.f, 0.f, 0.f, 0.f};
#pragma unroll
                for (int tj = 0; tj < 8; ++tj) {
                    if (tj <= lim) {
#pragma unroll
                        for (int r = 0; r < 4; ++r) {
                            float p = exp2f(sacc[ti][tj][r] - mrow[ti]);
                            rs[r] += p;
                            sacc[ti][tj][r] = p;
                        }
                    }
                }
                float rsum = (rs[0] + rs[1]) + (rs[2] + rs[3]);
                rsum += __shfl_xor(rsum, 16);
                rsum += __shfl_xor(rsum, 32);
                lrow[ti] += rsum;
            }

            // P -> LDS and O += P V, in two k-halves (Ps wave-private rows)
#pragma unroll
            for (int h2 = 0; h2 < 2; ++h2) {
                if (4 * h2 > lim) break;
#pragma unroll
                for (int ti = 0; ti < 2; ++ti) {
                    const int ql = wave * 32 + ti * 16 + l15;
#pragma unroll
                    for (int tjo = 0; tjo < 4; ++tjo) {
                        int tj = 4 * h2 + tjo;
                        if (tj <= lim) {
                            bf16x4 pv;
#pragma unroll
                            for (int r = 0; r < 4; ++r) pv[r] = (bf16)sacc[ti][tj][r];
                            *(bf16x4*)(&Ps[ql * 72 + tjo * 16 + quad * 4]) = pv;
                        }
                    }
                }
#pragma unroll
                for (int ks2 = 0; ks2 < 2; ++ks2) {
                    const int gks = 2 * h2 + ks2;
                    if (diag && gks > wave) break;
                    bf16x8 pf[2];
                    pf[0] = *(const bf16x8*)(&Ps[(wave * 32 + l15) * 72 + ks2 * 32 + quad * 8]);
                    pf[1] = *(const bf16x8*)(&Ps[(wave * 32 + 16 + l15) * 72 + ks2 * 32 + quad * 8]);
                    __builtin_amdgcn_s_setprio(1);
#pragma unroll
                    for (int nj = 0; nj < 4; ++nj) {
                        int pos = ((gks * 4 + quad) ^ l15) * 8;
                        bf16x8 vf = *(const bf16x8*)(&Vts[(nj * 16 + l15) * 128 + pos]);
                        oacc[0][nj] = __builtin_amdgcn_mfma_f32_16x16x32_bf16(pf[0], vf, oacc[0][nj], 0, 0, 0);
                        oacc[1][nj] = __builtin_amdgcn_mfma_f32_16x16x32_bf16(pf[1], vf, oacc[1][nj], 0, 0, 0);
                    }
                    __builtin_amdgcn_s_setprio(0);
                }
            }
        }

        // epilogue: O /= l ; O rows = quad*4+r, cols d = nj*16+l15
#pragma unroll
        for (int ti = 0; ti < 2; ++ti) {
#pragma unroll
            for (int r = 0; r < 4; ++r) {
                float lv = __shfl(lrow[ti], quad * 4 + r);
                float rl = 1.f / lv;
                int qrow = qt * 128 + wave * 32 + ti * 16 + quad * 4 + r;
#pragma unroll
                for (int nj = 0; nj < 4; ++nj) {
                    int d = nj * 16 + l15;
                    AO[((size_t)(bb * T_SEQ + qrow)) * D_MODEL + hh * HD + d] =
                        (bf16)(oacc[ti][nj][r] * rl);
                }
            }
        }
    }
}

extern "C" void kernel_launch(void* const* d_in, const int* in_sizes, int n_in,
                              void* d_out, int out_size, void* d_ws, size_t ws_size,
                              hipStream_t stream)
{
    const float* q  = (const float*)d_in[0];
    const float* k  = (const float*)d_in[1];
    const float* v  = (const float*)d_in[2];
    const float* wq = (const float*)d_in[3];
    const float* bq = (const float*)d_in[4];
    const float* wk = (const float*)d_in[5];
    const float* bk = (const float*)d_in[6];
    const float* wv = (const float*)d_in[7];
    const float* bv = (const float*)d_in[8];
    const float* wo = (const float*)d_in[9];
    const float* bo = (const float*)d_in[10];

    char* ws  = (char*)d_ws;
    char* dob = (char*)d_out;
    const size_t MB = 1024 * 1024;

    // ws: Wqb[0,2) Wkb[2,4) Wvb[4,6) Wob[6,8) Vb[8,24) Qh[24,40) Kh[40,56)
    //   AO reuses Vb's region [8,24) after the V-GEMM consumed Vb.
    // d_out (32 MB): Qb[0,16) Kb[16,32) -> V-GEMM writes Vt over [0,16)
    //   (Qb dead after QK-GEMM) -> O-GEMM writes final fp32 over everything.
    bf16* Wqb = (bf16*)(ws);
    bf16* Wkb = (bf16*)(ws + 2 * MB);
    bf16* Wvb = (bf16*)(ws + 4 * MB);
    bf16* Wob = (bf16*)(ws + 6 * MB);
    bf16* Vb  = (bf16*)(ws + 8 * MB);
    bf16* AO  = (bf16*)(ws + 8 * MB);
    bf16* Qh  = (bf16*)(ws + 24 * MB);
    bf16* Kh  = (bf16*)(ws + 40 * MB);
    bf16* Qb  = (bf16*)(dob);
    bf16* Kb  = (bf16*)(dob + 16 * MB);
    bf16* Vt  = (bf16*)(dob);

    const int NQ8 = M_ROWS * D_MODEL / 8;   // 1M
    const int NW8 = D_MODEL * D_MODEL / 8;  // 128K
    const float QSCALE = 0.18033688011112042f;  // (1/sqrt(64)) * log2(e)

    CvtArgs ca;
    ca.s[0] = q;  ca.d[0] = Qb;  ca.n[0] = NQ8;
    ca.s[1] = k;  ca.d[1] = Kb;  ca.n[1] = NQ8;
    ca.s[2] = v;  ca.d[2] = Vb;  ca.n[2] = NQ8;
    ca.s[3] = wq; ca.d[3] = Wqb; ca.n[3] = NW8;
    ca.s[4] = wk; ca.d[4] = Wkb; ca.n[4] = NW8;
    ca.s[5] = wv; ca.d[5] = Wvb; ca.n[5] = NW8;
    ca.s[6] = wo; ca.d[6] = Wob; ca.n[6] = NW8;

    GemmArgs gqk;
    gqk.A[0] = Qb; gqk.W[0] = Wqb; gqk.bias[0] = bq; gqk.Out[0] = (void*)Qh; gqk.scl[0] = QSCALE; gqk.omode[0] = 0;
    gqk.A[1] = Kb; gqk.W[1] = Wkb; gqk.bias[1] = bk; gqk.Out[1] = (void*)Kh; gqk.scl[1] = 1.0f;   gqk.omode[1] = 0;

    GemmArgs gv;
    gv.A[0] = Vb; gv.W[0] = Wvb; gv.bias[0] = bv; gv.Out[0] = (void*)Vt; gv.scl[0] = 1.0f; gv.omode[0] = 1;
    gv.A[1] = Vb; gv.W[1] = Wvb; gv.bias[1] = bv; gv.Out[1] = (void*)Vt; gv.scl[1] = 1.0f; gv.omode[1] = 1;

    GemmArgs go;
    go.A[0] = AO; go.W[0] = Wob; go.bias[0] = bo; go.Out[0] = d_out; go.scl[0] = 1.0f; go.omode[0] = 2;
    go.A[1] = AO; go.W[1] = Wob; go.bias[1] = bo; go.Out[1] = d_out; go.scl[1] = 1.0f; go.omode[1] = 2;

    hipLaunchKernelGGL(cvt7_kernel, dim3(512, 7), dim3(256), 0, stream, ca);
    hipLaunchKernelGGL(gemm_k, dim3(32, 8, 2), dim3(512), 0, stream, gqk);
    hipLaunchKernelGGL(gemm_k, dim3(32, 8, 1), dim3(512), 0, stream, gv);
    hipLaunchKernelGGL(attn_kernel, dim3(8, 64), dim3(256), 0, stream, Qh, Kh, Vt, AO);
    hipLaunchKernelGGL(gemm_k, dim3(32, 8, 1), dim3(512), 0, stream, go);
}